// Round 1
// baseline (724.502 us; speedup 1.0000x reference)
//
#include <hip/hip_runtime.h>
#include <math.h>

#define N_NODES 20000
#define N_EDGES 200000
#define DM 128
#define NH 8

// float atomic max via int/uint trick (works with -inf init; -0.0 edge case is
// softmax-shift-invariant so harmless)
__device__ __forceinline__ void atomicMaxF(float* addr, float val) {
  if (val >= 0.f) {
    atomicMax((int*)addr, __float_as_int(val));
  } else {
    atomicMin((unsigned int*)addr, __float_as_uint(val));
  }
}

// C[N,M] = A[N,128] @ B[128,M]; block = 128 threads, each block does 16 rows x 128 cols
template <int M>
__global__ void gemm_k128(const float* __restrict__ A, const float* __restrict__ B,
                          float* __restrict__ C, int N) {
  constexpr int ROWS = 16;
  __shared__ float As[ROWS][DM];
  const int c = blockIdx.x * 128 + threadIdx.x;
  const int r0 = blockIdx.y * ROWS;
  for (int i = threadIdx.x; i < ROWS * DM; i += 128) {
    int r = i >> 7, k = i & 127;
    As[r][k] = (r0 + r < N) ? A[(size_t)(r0 + r) * DM + k] : 0.f;
  }
  __syncthreads();
  float acc[ROWS];
#pragma unroll
  for (int r = 0; r < ROWS; ++r) acc[r] = 0.f;
  const float* Bc = B + c;
  for (int k = 0; k < DM; ++k) {
    float b = Bc[(size_t)k * M];
#pragma unroll
    for (int r = 0; r < ROWS; ++r) acc[r] += As[r][k] * b;
  }
#pragma unroll
  for (int r = 0; r < ROWS; ++r)
    if (r0 + r < N) C[(size_t)(r0 + r) * M + c] = acc[r];
}

// el[i] = dot(feat[i*HD : ], al[h]); er likewise. i = n*NH + h
__global__ void attn_scores(const float* __restrict__ feat, const float* __restrict__ al,
                            const float* __restrict__ ar, float* __restrict__ el,
                            float* __restrict__ er, int total, int HD) {
  int i = blockIdx.x * blockDim.x + threadIdx.x;
  if (i >= total) return;
  int h = i & (NH - 1);
  const float* f = feat + (size_t)i * HD;
  const float* alh = al + h * HD;
  const float* arh = ar + h * HD;
  float sl = 0.f, sr = 0.f;
  for (int d = 0; d < HD; ++d) {
    float v = f[d];
    sl += v * alh[d];
    sr += v * arh[d];
  }
  el[i] = sl;
  er[i] = sr;
}

__global__ void init_mz(float* __restrict__ m, float* __restrict__ z, int n) {
  int i = blockIdx.x * blockDim.x + threadIdx.x;
  if (i < n) {
    m[i] = -INFINITY;
    z[i] = 0.f;
  }
}

// per (edge, head): e = leaky_relu(el[src]+er[dst], 0.2); atomic max into m[dst,h]
__global__ void edge_logits(const int* __restrict__ src, const int* __restrict__ dst,
                            const float* __restrict__ el, const float* __restrict__ er,
                            float* __restrict__ eatt, float* __restrict__ m) {
  int i = blockIdx.x * blockDim.x + threadIdx.x;
  if (i >= N_EDGES * NH) return;
  int e = i >> 3, h = i & 7;
  int s = src[e], d = dst[e];
  float v = el[s * NH + h] + er[d * NH + h];
  v = v > 0.f ? v : 0.2f * v;
  eatt[i] = v;
  atomicMaxF(&m[d * NH + h], v);
}

// per (edge, head): p = exp(e - m[dst]); z[dst] += p
__global__ void edge_expsum(const int* __restrict__ dst, const float* __restrict__ m,
                            float* __restrict__ eatt, float* __restrict__ z) {
  int i = blockIdx.x * blockDim.x + threadIdx.x;
  if (i >= N_EDGES * NH) return;
  int e = i >> 3, h = i & 7;
  int d = dst[e];
  float p = expf(eatt[i] - m[d * NH + h]);
  eatt[i] = p;
  atomicAdd(&z[d * NH + h], p);
}

// layers 0/1 (hd=16): per (edge, d0..127): rst[dst,d] += feat[src,d] * a[e, d>>4]
__global__ void edge_agg_small(const int* __restrict__ src, const int* __restrict__ dst,
                               const float* __restrict__ feat, const float* __restrict__ p,
                               const float* __restrict__ z, float* __restrict__ rst) {
  long long i = (long long)blockIdx.x * blockDim.x + threadIdx.x;
  if (i >= (long long)N_EDGES * DM) return;
  int e = (int)(i >> 7), d = (int)(i & 127);
  int h = d >> 4;
  int s = src[e], t = dst[e];
  float a = p[e * NH + h] / z[t * NH + h];
  atomicAdd(&rst[(size_t)t * DM + d], feat[(size_t)s * DM + d] * a);
}

// last layer (hd=128): fold head-mean: acc[dst,d] += (1/8) * sum_h feat[src,h,d]*a[e,h]
__global__ void edge_agg_last(const int* __restrict__ src, const int* __restrict__ dst,
                              const float* __restrict__ feat, const float* __restrict__ p,
                              const float* __restrict__ z, float* __restrict__ acc) {
  long long i = (long long)blockIdx.x * blockDim.x + threadIdx.x;
  if (i >= (long long)N_EDGES * DM) return;
  int e = (int)(i >> 7), d = (int)(i & 127);
  int s = src[e], t = dst[e];
  float sum = 0.f;
#pragma unroll
  for (int h = 0; h < NH; ++h) {
    float a = p[e * NH + h] / z[t * NH + h];
    sum += feat[(size_t)s * (NH * DM) + h * DM + d] * a;
  }
  atomicAdd(&acc[(size_t)t * DM + d], sum * 0.125f);
}

// h += elu(rst + b)
__global__ void update_h(float* __restrict__ h, const float* __restrict__ rst,
                         const float* __restrict__ b, int total) {
  int i = blockIdx.x * blockDim.x + threadIdx.x;
  if (i >= total) return;
  int d = i & 127;
  float v = rst[i] + b[d];
  float e = v > 0.f ? v : expm1f(v);
  h[i] += e;
}

// out = h + acc + mean_h(b_last)
__global__ void final_out(const float* __restrict__ h, const float* __restrict__ acc,
                          const float* __restrict__ bl, float* __restrict__ out, int total) {
  int i = blockIdx.x * blockDim.x + threadIdx.x;
  if (i >= total) return;
  int d = i & 127;
  float mb = 0.f;
#pragma unroll
  for (int hh = 0; hh < NH; ++hh) mb += bl[hh * DM + d];
  out[i] = h[i] + acc[i] + mb * 0.125f;
}

extern "C" void kernel_launch(void* const* d_in, const int* in_sizes, int n_in,
                              void* d_out, int out_size, void* d_ws, size_t ws_size,
                              hipStream_t stream) {
  const float* x = (const float*)d_in[0];
  const int* src = (const int*)d_in[1];
  const int* dst = (const int*)d_in[2];
  const float* Ws = (const float*)d_in[3];
  const float* als = (const float*)d_in[4];
  const float* ars = (const float*)d_in[5];
  const float* bs = (const float*)d_in[6];
  const float* W_last = (const float*)d_in[7];
  const float* al_last = (const float*)d_in[8];
  const float* ar_last = (const float*)d_in[9];
  const float* b_last = (const float*)d_in[10];
  float* out = (float*)d_out;

  // workspace layout (fp32), ~112 MB total
  float* h = (float*)d_ws;                              // N*128
  float* feat = h + (size_t)N_NODES * DM;               // N*1024 (last layer), first N*128 for layers 0/1
  float* el = feat + (size_t)N_NODES * NH * DM;         // N*8
  float* er = el + N_NODES * NH;                        // N*8
  float* m = er + N_NODES * NH;                         // N*8
  float* z = m + N_NODES * NH;                          // N*8
  float* eatt = z + N_NODES * NH;                       // E*8
  float* rst = eatt + (size_t)N_EDGES * NH;             // N*128 (also last-layer acc)

  const int NHt = N_NODES * NH;                 // 160000
  const long long EH = (long long)N_EDGES * NH; // 1.6M
  const long long ED = (long long)N_EDGES * DM; // 25.6M
  const int ND = N_NODES * DM;                  // 2.56M

  hipMemcpyAsync(h, x, sizeof(float) * (size_t)ND, hipMemcpyDeviceToDevice, stream);

  for (int layer = 0; layer < 2; ++layer) {
    dim3 gg(1, (N_NODES + 15) / 16);
    gemm_k128<DM><<<gg, 128, 0, stream>>>(h, Ws + (size_t)layer * DM * DM, feat, N_NODES);
    attn_scores<<<(NHt + 255) / 256, 256, 0, stream>>>(
        feat, als + layer * NH * 16, ars + layer * NH * 16, el, er, NHt, 16);
    init_mz<<<(NHt + 255) / 256, 256, 0, stream>>>(m, z, NHt);
    hipMemsetAsync(rst, 0, sizeof(float) * (size_t)ND, stream);
    edge_logits<<<(int)((EH + 255) / 256), 256, 0, stream>>>(src, dst, el, er, eatt, m);
    edge_expsum<<<(int)((EH + 255) / 256), 256, 0, stream>>>(dst, m, eatt, z);
    edge_agg_small<<<(int)((ED + 255) / 256), 256, 0, stream>>>(src, dst, feat, eatt, z, rst);
    update_h<<<(ND + 255) / 256, 256, 0, stream>>>(h, rst, bs + layer * DM, ND);
  }

  // last layer: hd = 128, mean over heads folded into aggregation
  {
    dim3 gg(NH, (N_NODES + 15) / 16);
    gemm_k128<NH * DM><<<gg, 128, 0, stream>>>(h, W_last, feat, N_NODES);
    attn_scores<<<(NHt + 255) / 256, 256, 0, stream>>>(feat, al_last, ar_last, el, er, NHt, DM);
    init_mz<<<(NHt + 255) / 256, 256, 0, stream>>>(m, z, NHt);
    hipMemsetAsync(rst, 0, sizeof(float) * (size_t)ND, stream);
    edge_logits<<<(int)((EH + 255) / 256), 256, 0, stream>>>(src, dst, el, er, eatt, m);
    edge_expsum<<<(int)((EH + 255) / 256), 256, 0, stream>>>(dst, m, eatt, z);
    edge_agg_last<<<(int)((ED + 255) / 256), 256, 0, stream>>>(src, dst, feat, eatt, z, rst);
    final_out<<<(ND + 255) / 256, 256, 0, stream>>>(h, rst, b_last, out, ND);
  }
}

// Round 2
// 463.850 us; speedup vs baseline: 1.5619x; 1.5619x over previous
//
#include <hip/hip_runtime.h>
#include <math.h>

#define N_NODES 20000
#define N_EDGES 200000
#define DM 128
#define NH 8

__device__ __forceinline__ void atomicMaxF(float* addr, float val) {
  if (val >= 0.f) {
    atomicMax((int*)addr, __float_as_int(val));
  } else {
    atomicMin((unsigned int*)addr, __float_as_uint(val));
  }
}

// ---------------- CSR build (dst-sorted) ----------------
__global__ void count_deg(const int* __restrict__ dst, int* __restrict__ deg) {
  int e = blockIdx.x * blockDim.x + threadIdx.x;
  if (e < N_EDGES) atomicAdd(&deg[dst[e]], 1);
}

__global__ void scan_deg(const int* __restrict__ deg, int* __restrict__ off,
                         int* __restrict__ cursor) {
  __shared__ int part[1024];
  const int tid = threadIdx.x;
  const int CHUNK = (N_NODES + 1023) / 1024;  // 20
  int base = tid * CHUNK;
  int s = 0;
  for (int i = 0; i < CHUNK; ++i) {
    int idx = base + i;
    if (idx < N_NODES) s += deg[idx];
  }
  part[tid] = s;
  __syncthreads();
  for (int ofs = 1; ofs < 1024; ofs <<= 1) {
    int v = (tid >= ofs) ? part[tid - ofs] : 0;
    __syncthreads();
    part[tid] += v;
    __syncthreads();
  }
  int run = (tid > 0) ? part[tid - 1] : 0;
  for (int i = 0; i < CHUNK; ++i) {
    int idx = base + i;
    if (idx < N_NODES) {
      off[idx] = run;
      cursor[idx] = run;
      run += deg[idx];
    }
  }
  if (tid == 0) off[N_NODES] = part[1023];
}

__global__ void scatter_e(const int* __restrict__ dst, int* __restrict__ cursor,
                          int* __restrict__ csr) {
  int e = blockIdx.x * blockDim.x + threadIdx.x;
  if (e < N_EDGES) {
    int p = atomicAdd(&cursor[dst[e]], 1);
    csr[p] = e;
  }
}

// ---------------- tiled fp32 GEMM: C[N,128] = A[N,K] @ B[K,128] ----------------
template <int K, bool LAST>
__global__ __launch_bounds__(256) void gemm_tile(const float* __restrict__ A,
                                                 const float* __restrict__ B,
                                                 const float* __restrict__ hres,
                                                 const float* __restrict__ mb,
                                                 float* __restrict__ C, int N) {
  constexpr int BM = 64, BK = 16;
  __shared__ float As[BK][BM + 4];
  __shared__ float Bs[BK][128];
  const int tid = threadIdx.x;
  const int tx = tid & 15;   // col group: 8 cols
  const int ty = tid >> 4;   // row group: 4 rows
  const int r0 = blockIdx.x * BM;

  float acc[4][8];
#pragma unroll
  for (int i = 0; i < 4; ++i)
#pragma unroll
    for (int j = 0; j < 8; ++j) acc[i][j] = 0.f;

  const int lrow = tid >> 2;        // 0..63
  const int lk4 = (tid & 3) << 2;   // 0,4,8,12
  const int brow = tid >> 4;        // 0..15
  const int bcol = (tid & 15) << 3; // 0..120

  for (int k0 = 0; k0 < K; k0 += BK) {
    float4 av = make_float4(0.f, 0.f, 0.f, 0.f);
    if (r0 + lrow < N) av = *(const float4*)&A[(size_t)(r0 + lrow) * K + k0 + lk4];
    As[lk4 + 0][lrow] = av.x;
    As[lk4 + 1][lrow] = av.y;
    As[lk4 + 2][lrow] = av.z;
    As[lk4 + 3][lrow] = av.w;
    *(float4*)&Bs[brow][bcol] = *(const float4*)&B[(size_t)(k0 + brow) * 128 + bcol];
    *(float4*)&Bs[brow][bcol + 4] = *(const float4*)&B[(size_t)(k0 + brow) * 128 + bcol + 4];
    __syncthreads();
#pragma unroll
    for (int kk = 0; kk < BK; ++kk) {
      float4 a = *(const float4*)&As[kk][ty * 4];
      float4 b0 = *(const float4*)&Bs[kk][tx * 8];
      float4 b1 = *(const float4*)&Bs[kk][tx * 8 + 4];
      float ar[4] = {a.x, a.y, a.z, a.w};
      float br[8] = {b0.x, b0.y, b0.z, b0.w, b1.x, b1.y, b1.z, b1.w};
#pragma unroll
      for (int i = 0; i < 4; ++i)
#pragma unroll
        for (int j = 0; j < 8; ++j) acc[i][j] += ar[i] * br[j];
    }
    __syncthreads();
  }

#pragma unroll
  for (int i = 0; i < 4; ++i) {
    int row = r0 + ty * 4 + i;
    if (row >= N) continue;
    float v[8];
#pragma unroll
    for (int j = 0; j < 8; ++j) {
      int col = tx * 8 + j;
      if (LAST)
        v[j] = hres[(size_t)row * 128 + col] + acc[i][j] + mb[col];
      else
        v[j] = acc[i][j];
    }
    *(float4*)&C[(size_t)row * 128 + tx * 8] = make_float4(v[0], v[1], v[2], v[3]);
    *(float4*)&C[(size_t)row * 128 + tx * 8 + 4] = make_float4(v[4], v[5], v[6], v[7]);
  }
}

// ---------------- attention scores ----------------
// layers 0/1: el/er from feat (N,128), head h owns cols h*16..
__global__ void attn_scores(const float* __restrict__ feat, const float* __restrict__ al,
                            const float* __restrict__ ar, float* __restrict__ el,
                            float* __restrict__ er) {
  int i = blockIdx.x * blockDim.x + threadIdx.x;
  if (i >= N_NODES * NH) return;
  int h = i & 7;
  const float* f = feat + (size_t)i * 16;
  const float* alh = al + h * 16;
  const float* arh = ar + h * 16;
  float sl = 0.f, sr = 0.f;
#pragma unroll
  for (int d = 0; d < 16; ++d) {
    float v = f[d];
    sl += v * alh[d];
    sr += v * arh[d];
  }
  el[i] = sl;
  er[i] = sr;
}

// last layer: wl[k,h] = sum_d W[k, h*128+d]*al[h,d]
__global__ void wl_build(const float* __restrict__ W, const float* __restrict__ al,
                         const float* __restrict__ ar, float* __restrict__ wl,
                         float* __restrict__ wr) {
  int i = blockIdx.x * blockDim.x + threadIdx.x;
  if (i >= 128 * 8) return;
  int k = i >> 3, h = i & 7;
  float sl = 0.f, sr = 0.f;
  for (int d = 0; d < 128; ++d) {
    float w = W[(size_t)k * 1024 + h * 128 + d];
    sl += w * al[h * 128 + d];
    sr += w * ar[h * 128 + d];
  }
  wl[k * 8 + h] = sl;
  wr[k * 8 + h] = sr;
}

// el/er = h @ wl / wr   (N,128)@(128,8)
__global__ void el_er_last(const float* __restrict__ hin, const float* __restrict__ wl,
                           const float* __restrict__ wr, float* __restrict__ el,
                           float* __restrict__ er) {
  int i = blockIdx.x * blockDim.x + threadIdx.x;
  if (i >= N_NODES * NH) return;
  int n = i >> 3, h = i & 7;
  const float* hr = hin + (size_t)n * 128;
  float sl = 0.f, sr = 0.f;
  for (int k = 0; k < 128; ++k) {
    float v = hr[k];
    sl += v * wl[k * 8 + h];
    sr += v * wr[k * 8 + h];
  }
  el[i] = sl;
  er[i] = sr;
}

// W_perm[(h*128+k), d] = W_last[k, h*128+d]/8 ; mb[d] = mean_h b_last[h*128+d]
__global__ void wperm_build(const float* __restrict__ W, const float* __restrict__ b,
                            float* __restrict__ Wp, float* __restrict__ mb) {
  int i = blockIdx.x * blockDim.x + threadIdx.x;
  if (i < 1024 * 128) {
    int row = i >> 7;
    int d = i & 127;
    int hh = row >> 7, k = row & 127;
    Wp[i] = W[(size_t)k * 1024 + hh * 128 + d] * 0.125f;
  }
  if (i < 128) {
    float s = 0.f;
#pragma unroll
    for (int hh = 0; hh < 8; ++hh) s += b[hh * 128 + i];
    mb[i] = s * 0.125f;
  }
}

// ---------------- edge softmax (atomic, small) ----------------
__global__ void init_mz(float* __restrict__ m, float* __restrict__ z, int n) {
  int i = blockIdx.x * blockDim.x + threadIdx.x;
  if (i < n) {
    m[i] = -INFINITY;
    z[i] = 0.f;
  }
}

__global__ void edge_logits(const int* __restrict__ src, const int* __restrict__ dst,
                            const float* __restrict__ el, const float* __restrict__ er,
                            float* __restrict__ eatt, float* __restrict__ m) {
  int i = blockIdx.x * blockDim.x + threadIdx.x;
  if (i >= N_EDGES * NH) return;
  int e = i >> 3, h = i & 7;
  int s = src[e], d = dst[e];
  float v = el[s * NH + h] + er[d * NH + h];
  v = v > 0.f ? v : 0.2f * v;
  eatt[i] = v;
  atomicMaxF(&m[d * NH + h], v);
}

__global__ void edge_expsum(const int* __restrict__ dst, const float* __restrict__ m,
                            float* __restrict__ eatt, float* __restrict__ z) {
  int i = blockIdx.x * blockDim.x + threadIdx.x;
  if (i >= N_EDGES * NH) return;
  int e = i >> 3, h = i & 7;
  int d = dst[e];
  float p = expf(eatt[i] - m[d * NH + h]);
  eatt[i] = p;
  atomicAdd(&z[d * NH + h], p);
}

// ---------------- CSR aggregation ----------------
// layers 0/1: per node t, thread d: h[t,d] += elu(sum_e a[e,d>>4]*feat[src,d] + bias[d])
__global__ __launch_bounds__(128) void agg_small(
    const int* __restrict__ off, const int* __restrict__ csr, const int* __restrict__ src,
    const float* __restrict__ feat, const float* __restrict__ eatt,
    const float* __restrict__ z, const float* __restrict__ bias, float* __restrict__ hio) {
  constexpr int CH = 64;
  __shared__ float a_lds[CH][8];
  __shared__ int s_lds[CH];
  const int t = blockIdx.x;
  const int d = threadIdx.x;
  const int h = d >> 4;
  const int beg = off[t], end = off[t + 1];
  float zi = (end > beg) ? 1.f / z[t * 8 + h] : 0.f;
  float acc = 0.f;
  for (int base = beg; base < end; base += CH) {
    int n = min(CH, end - base);
    for (int i = d; i < n; i += 128) s_lds[i] = src[csr[base + i]];
    for (int i = d; i < n * 8; i += 128) {
      int el_ = i >> 3, hh = i & 7;
      a_lds[el_][hh] = eatt[(size_t)csr[base + el_] * 8 + hh];
    }
    __syncthreads();
    for (int i = 0; i < n; ++i)
      acc += a_lds[i][h] * feat[(size_t)s_lds[i] * 128 + d];
    __syncthreads();
  }
  float v = acc * zi + bias[d];
  float e = v > 0.f ? v : expm1f(v);
  hio[(size_t)t * 128 + d] += e;
}

// last layer: g[t, h*128+k] = sum_e a[e,h] * hin[src, k]
__global__ __launch_bounds__(128) void agg_last(
    const int* __restrict__ off, const int* __restrict__ csr, const int* __restrict__ src,
    const float* __restrict__ hin, const float* __restrict__ eatt,
    const float* __restrict__ z, float* __restrict__ g) {
  constexpr int CH = 64;
  __shared__ float a_lds[CH][8];
  __shared__ int s_lds[CH];
  __shared__ float zinv[8];
  const int t = blockIdx.x;
  const int k = threadIdx.x;
  const int beg = off[t], end = off[t + 1];
  if (k < 8) zinv[k] = (end > beg) ? 1.f / z[t * 8 + k] : 0.f;
  __syncthreads();
  float acc[8];
#pragma unroll
  for (int h = 0; h < 8; ++h) acc[h] = 0.f;
  for (int base = beg; base < end; base += CH) {
    int n = min(CH, end - base);
    for (int i = k; i < n; i += 128) s_lds[i] = src[csr[base + i]];
    for (int i = k; i < n * 8; i += 128) {
      int el_ = i >> 3, hh = i & 7;
      a_lds[el_][hh] = eatt[(size_t)csr[base + el_] * 8 + hh] * zinv[hh];
    }
    __syncthreads();
    for (int i = 0; i < n; ++i) {
      float hv = hin[(size_t)s_lds[i] * 128 + k];
#pragma unroll
      for (int h = 0; h < 8; ++h) acc[h] += a_lds[i][h] * hv;
    }
    __syncthreads();
  }
#pragma unroll
  for (int h = 0; h < 8; ++h) g[(size_t)t * 1024 + h * 128 + k] = acc[h];
}

extern "C" void kernel_launch(void* const* d_in, const int* in_sizes, int n_in,
                              void* d_out, int out_size, void* d_ws, size_t ws_size,
                              hipStream_t stream) {
  const float* x = (const float*)d_in[0];
  const int* src = (const int*)d_in[1];
  const int* dst = (const int*)d_in[2];
  const float* Ws = (const float*)d_in[3];
  const float* als = (const float*)d_in[4];
  const float* ars = (const float*)d_in[5];
  const float* bs = (const float*)d_in[6];
  const float* W_last = (const float*)d_in[7];
  const float* al_last = (const float*)d_in[8];
  const float* ar_last = (const float*)d_in[9];
  const float* b_last = (const float*)d_in[10];
  float* out = (float*)d_out;

  // ---- workspace layout (floats) ----
  float* h = (float*)d_ws;                         // N*128
  float* g = h + (size_t)N_NODES * DM;             // N*1024 (feat for layers 0/1 aliases g)
  float* feat = g;
  float* el = g + (size_t)N_NODES * NH * DM;       // N*8
  float* er = el + N_NODES * NH;
  float* m = er + N_NODES * NH;
  float* z = m + N_NODES * NH;
  float* eatt = z + N_NODES * NH;                  // E*8
  float* wl = eatt + (size_t)N_EDGES * NH;         // 1024
  float* wr = wl + 1024;                           // 1024
  float* Wp = wr + 1024;                           // 1024*128
  float* mb = Wp + 1024 * 128;                     // 128
  int* deg = (int*)(mb + 128);                     // N
  int* off = deg + N_NODES;                        // N+1
  int* cursor = off + N_NODES + 1;                 // N
  int* csr = cursor + N_NODES;                     // E

  const int NHt = N_NODES * NH;
  const int EH = N_EDGES * NH;
  const int ND = N_NODES * DM;

  // CSR build
  hipMemsetAsync(deg, 0, sizeof(int) * N_NODES, stream);
  count_deg<<<(N_EDGES + 255) / 256, 256, 0, stream>>>(dst, deg);
  scan_deg<<<1, 1024, 0, stream>>>(deg, off, cursor);
  scatter_e<<<(N_EDGES + 255) / 256, 256, 0, stream>>>(dst, cursor, csr);

  // last-layer folded weights (independent, run early)
  wl_build<<<4, 256, 0, stream>>>(W_last, al_last, ar_last, wl, wr);
  wperm_build<<<512, 256, 0, stream>>>(W_last, b_last, Wp, mb);

  hipMemcpyAsync(h, x, sizeof(float) * (size_t)ND, hipMemcpyDeviceToDevice, stream);

  const int GB = (N_NODES + 63) / 64;
  for (int layer = 0; layer < 2; ++layer) {
    gemm_tile<DM, false><<<GB, 256, 0, stream>>>(h, Ws + (size_t)layer * DM * DM, nullptr,
                                                 nullptr, feat, N_NODES);
    attn_scores<<<(NHt + 255) / 256, 256, 0, stream>>>(feat, als + layer * NH * 16,
                                                       ars + layer * NH * 16, el, er);
    init_mz<<<(NHt + 255) / 256, 256, 0, stream>>>(m, z, NHt);
    edge_logits<<<(EH + 255) / 256, 256, 0, stream>>>(src, dst, el, er, eatt, m);
    edge_expsum<<<(EH + 255) / 256, 256, 0, stream>>>(dst, m, eatt, z);
    agg_small<<<N_NODES, 128, 0, stream>>>(off, csr, src, feat, eatt, z, bs + layer * DM, h);
  }

  // last layer (aggregate-then-transform)
  el_er_last<<<(NHt + 255) / 256, 256, 0, stream>>>(h, wl, wr, el, er);
  init_mz<<<(NHt + 255) / 256, 256, 0, stream>>>(m, z, NHt);
  edge_logits<<<(EH + 255) / 256, 256, 0, stream>>>(src, dst, el, er, eatt, m);
  edge_expsum<<<(EH + 255) / 256, 256, 0, stream>>>(dst, m, eatt, z);
  agg_last<<<N_NODES, 128, 0, stream>>>(off, csr, src, h, eatt, z, g);
  gemm_tile<NH * DM, true><<<GB, 256, 0, stream>>>(g, Wp, h, mb, out, N_NODES);
}

// Round 3
// 297.934 us; speedup vs baseline: 2.4318x; 1.5569x over previous
//
#include <hip/hip_runtime.h>
#include <math.h>

#define N_NODES 20000
#define N_EDGES 200000
#define DM 128
#define NH 8

typedef __attribute__((ext_vector_type(8))) short bf16x8;
typedef __attribute__((ext_vector_type(4))) float f32x4;

__device__ __forceinline__ unsigned short f2b(float f) {
  unsigned int u = __float_as_uint(f);
  unsigned int r = (u + 0x7FFFu + ((u >> 16) & 1u)) >> 16;  // RNE
  return (unsigned short)r;
}
__device__ __forceinline__ float b2f(unsigned short s) {
  return __uint_as_float(((unsigned int)s) << 16);
}

// ---------------- CSR build (dst-sorted) ----------------
__global__ void count_deg(const int* __restrict__ dst, int* __restrict__ deg) {
  int e = blockIdx.x * blockDim.x + threadIdx.x;
  if (e < N_EDGES) atomicAdd(&deg[dst[e]], 1);
}

__global__ void scan_deg(const int* __restrict__ deg, int* __restrict__ off,
                         int* __restrict__ cursor) {
  __shared__ int part[1024];
  const int tid = threadIdx.x;
  const int CHUNK = (N_NODES + 1023) / 1024;  // 20
  int base = tid * CHUNK;
  int s = 0;
  for (int i = 0; i < CHUNK; ++i) {
    int idx = base + i;
    if (idx < N_NODES) s += deg[idx];
  }
  part[tid] = s;
  __syncthreads();
  for (int ofs = 1; ofs < 1024; ofs <<= 1) {
    int v = (tid >= ofs) ? part[tid - ofs] : 0;
    __syncthreads();
    part[tid] += v;
    __syncthreads();
  }
  int run = (tid > 0) ? part[tid - 1] : 0;
  for (int i = 0; i < CHUNK; ++i) {
    int idx = base + i;
    if (idx < N_NODES) {
      off[idx] = run;
      cursor[idx] = run;
      run += deg[idx];
    }
  }
  if (tid == 0) off[N_NODES] = part[1023];
}

__global__ void scatter_e(const int* __restrict__ src, const int* __restrict__ dst,
                          int* __restrict__ cursor, int* __restrict__ csr_src) {
  int e = blockIdx.x * blockDim.x + threadIdx.x;
  if (e < N_EDGES) {
    int p = atomicAdd(&cursor[dst[e]], 1);
    csr_src[p] = src[e];
  }
}

// ---------------- casts / weight prep ----------------
__global__ void cast_x(const float* __restrict__ x, float* __restrict__ h,
                       unsigned short* __restrict__ hb) {
  int i = blockIdx.x * blockDim.x + threadIdx.x;
  if (i < N_NODES * DM) {
    float v = x[i];
    h[i] = v;
    hb[i] = f2b(v);
  }
}

// B fragment swizzle: Bsz[((ks*8+f)*64+l)*8+j] = B[ks*32+(l>>4)*8+j][f*16+(l&15)]
// layers 0/1 (K=128, 2 layers in one launch)
__global__ void wswz_small(const float* __restrict__ Ws, unsigned short* __restrict__ wsz) {
  int i = blockIdx.x * blockDim.x + threadIdx.x;
  if (i >= 2 * 16384) return;
  int layer = i >> 14;
  int r = i & 16383;
  int j = r & 7, l = (r >> 3) & 63, f = (r >> 9) & 7, ks = r >> 12;  // ks 0..3
  int k = ks * 32 + ((l >> 4) << 3) + j;
  int n = f * 16 + (l & 15);
  wsz[i] = f2b(Ws[(size_t)layer * 16384 + k * 128 + n]);
}

// last layer: B row r = h*128+k maps to W_last[k, h*128+d] * 0.125
__global__ void wswz_last(const float* __restrict__ W, unsigned short* __restrict__ wpsz) {
  int i = blockIdx.x * blockDim.x + threadIdx.x;
  if (i >= 131072) return;
  int j = i & 7, l = (i >> 3) & 63, f = (i >> 9) & 7, ks = i >> 12;  // ks 0..31
  int k = ks * 32 + ((l >> 4) << 3) + j;                             // 0..1023
  int n = f * 16 + (l & 15);
  int h_ = k >> 7, ko = k & 127;
  wpsz[i] = f2b(W[(size_t)ko * 1024 + h_ * 128 + n] * 0.125f);
}

// wl[k,h] = sum_d W[k,h*128+d]*al[h,d]; mb[d] = mean_h b[h*128+d]
__global__ void wl_build(const float* __restrict__ W, const float* __restrict__ al,
                         const float* __restrict__ ar, const float* __restrict__ b,
                         float* __restrict__ wl, float* __restrict__ wr,
                         float* __restrict__ mb) {
  int i = blockIdx.x * blockDim.x + threadIdx.x;
  if (i >= 1024) return;
  int k = i >> 3, h = i & 7;
  float sl = 0.f, sr = 0.f;
  for (int d = 0; d < 128; ++d) {
    float w = W[(size_t)k * 1024 + h * 128 + d];
    sl += w * al[h * 128 + d];
    sr += w * ar[h * 128 + d];
  }
  wl[k * 8 + h] = sl;
  wr[k * 8 + h] = sr;
  if (i < 128) {
    float s = 0.f;
#pragma unroll
    for (int hh = 0; hh < 8; ++hh) s += b[hh * 128 + i];
    mb[i] = s * 0.125f;
  }
}

// ---------------- MFMA GEMM: C[N,128] = A_bf16[N,K] @ Bsz_bf16 ----------------
// block 256 = 4 waves; tile 32 rows x 128 cols; wave (wr,wc): rows wr*16.., cols wc*64..
template <int K, bool LAST>
__global__ __launch_bounds__(256) void gemm_mfma(const unsigned short* __restrict__ A,
                                                 const unsigned short* __restrict__ Bsz,
                                                 const float* __restrict__ hres,
                                                 const float* __restrict__ mb,
                                                 unsigned short* __restrict__ Cb,
                                                 float* __restrict__ Cf) {
  const int tid = threadIdx.x;
  const int lane = tid & 63;
  const int wid = tid >> 6;
  const int wr = wid & 1, wc = wid >> 1;
  const int r0 = blockIdx.x * 32;
  const int arow = r0 + wr * 16 + (lane & 15);
  const int kg = lane >> 4;

  f32x4 acc[4];
#pragma unroll
  for (int fi = 0; fi < 4; ++fi) acc[fi] = {0.f, 0.f, 0.f, 0.f};

  const bf16x8* Ap = (const bf16x8*)(A + (size_t)arow * K + kg * 8);
  for (int ks = 0; ks < K / 32; ++ks) {
    bf16x8 a = Ap[ks * 4];
#pragma unroll
    for (int fi = 0; fi < 4; ++fi) {
      int f = wc * 4 + fi;
      bf16x8 b = *(const bf16x8*)(Bsz + (((size_t)(ks * 8 + f) * 64 + lane) << 3));
      acc[fi] = __builtin_amdgcn_mfma_f32_16x16x32_bf16(a, b, acc[fi], 0, 0, 0);
    }
  }

  const int rbase = r0 + wr * 16 + (lane >> 4) * 4;
#pragma unroll
  for (int fi = 0; fi < 4; ++fi) {
    int col = wc * 64 + fi * 16 + (lane & 15);
#pragma unroll
    for (int r = 0; r < 4; ++r) {
      int row = rbase + r;
      float v = acc[fi][r];
      if (LAST)
        Cf[(size_t)row * DM + col] = v + hres[(size_t)row * DM + col] + mb[col];
      else
        Cb[(size_t)row * DM + col] = f2b(v);
    }
  }
}

// ---------------- attention scores ----------------
// layers 0/1: feat bf16 (N,128); i = n*8+h -> row chunk feat[i*16..]
__global__ void attn_scores(const unsigned short* __restrict__ feat,
                            const float* __restrict__ al, const float* __restrict__ ar,
                            float* __restrict__ el, float* __restrict__ er) {
  int i = blockIdx.x * blockDim.x + threadIdx.x;
  if (i >= N_NODES * NH) return;
  int h = i & 7;
  const unsigned short* f = feat + (size_t)i * 16;
  const float* alh = al + h * 16;
  const float* arh = ar + h * 16;
  float sl = 0.f, sr = 0.f;
#pragma unroll
  for (int d = 0; d < 16; ++d) {
    float v = b2f(f[d]);
    sl += v * alh[d];
    sr += v * arh[d];
  }
  el[i] = sl;
  er[i] = sr;
}

// last layer: el/er = h @ wl/wr  (fp32 h)
__global__ void el_er_last(const float* __restrict__ hin, const float* __restrict__ wl,
                           const float* __restrict__ wr, float* __restrict__ el,
                           float* __restrict__ er) {
  int i = blockIdx.x * blockDim.x + threadIdx.x;
  if (i >= N_NODES * NH) return;
  int n = i >> 3, h = i & 7;
  const float* hr = hin + (size_t)n * 128;
  float sl = 0.f, sr = 0.f;
  for (int k = 0; k < 128; ++k) {
    float v = hr[k];
    sl += v * wl[k * 8 + h];
    sr += v * wr[k * 8 + h];
  }
  el[i] = sl;
  er[i] = sr;
}

// ---------------- CSR edge softmax (no atomics): p = alpha (normalized) ----------------
__global__ void edge_softmax(const int* __restrict__ off, const int* __restrict__ csr_src,
                             const float* __restrict__ el, const float* __restrict__ er,
                             float* __restrict__ p) {
  int i = blockIdx.x * blockDim.x + threadIdx.x;
  if (i >= N_NODES * NH) return;
  int t = i >> 3, h = i & 7;
  int beg = off[t], end = off[t + 1];
  float ert = er[i];
  float m = -INFINITY;
  for (int pos = beg; pos < end; ++pos) {
    int s = csr_src[pos];
    float v = el[s * 8 + h] + ert;
    v = v > 0.f ? v : 0.2f * v;
    p[(size_t)pos * 8 + h] = v;
    m = fmaxf(m, v);
  }
  float z = 0.f;
  for (int pos = beg; pos < end; ++pos) {
    float v = expf(p[(size_t)pos * 8 + h] - m);
    z += v;
    p[(size_t)pos * 8 + h] = v;
  }
  float zi = 1.f / z;
  for (int pos = beg; pos < end; ++pos) p[(size_t)pos * 8 + h] *= zi;
}

// ---------------- CSR aggregation ----------------
// layers 0/1: h[t,d] += elu(sum a*feat + bias); hb = bf16(h)
__global__ __launch_bounds__(128) void agg_small(
    const int* __restrict__ off, const int* __restrict__ csr_src,
    const unsigned short* __restrict__ feat, const float* __restrict__ p,
    const float* __restrict__ bias, float* __restrict__ h, unsigned short* __restrict__ hb) {
  const int t = blockIdx.x;
  const int d = threadIdx.x;
  const int hh = d >> 4;
  const int beg = off[t], end = off[t + 1];
  float acc = 0.f;
  for (int pos = beg; pos < end; ++pos) {
    int s = csr_src[pos];
    acc += p[(size_t)pos * 8 + hh] * b2f(feat[(size_t)s * 128 + d]);
  }
  float v = acc + bias[d];
  float e = v > 0.f ? v : expm1f(v);
  size_t idx = (size_t)t * 128 + d;
  float nh = h[idx] + e;
  h[idx] = nh;
  hb[idx] = f2b(nh);
}

// last layer: g[t, h*128+k] = bf16( sum a[e,h] * hb[src,k] )
__global__ __launch_bounds__(128) void agg_last(
    const int* __restrict__ off, const int* __restrict__ csr_src,
    const unsigned short* __restrict__ hb, const float* __restrict__ p,
    unsigned short* __restrict__ g) {
  const int t = blockIdx.x;
  const int k = threadIdx.x;
  const int beg = off[t], end = off[t + 1];
  float acc[8];
#pragma unroll
  for (int h = 0; h < 8; ++h) acc[h] = 0.f;
  for (int pos = beg; pos < end; ++pos) {
    int s = csr_src[pos];
    float hv = b2f(hb[(size_t)s * 128 + k]);
    const float* pp = p + (size_t)pos * 8;
#pragma unroll
    for (int h = 0; h < 8; ++h) acc[h] += pp[h] * hv;
  }
#pragma unroll
  for (int h = 0; h < 8; ++h) g[(size_t)t * 1024 + h * 128 + k] = f2b(acc[h]);
}

extern "C" void kernel_launch(void* const* d_in, const int* in_sizes, int n_in,
                              void* d_out, int out_size, void* d_ws, size_t ws_size,
                              hipStream_t stream) {
  const float* x = (const float*)d_in[0];
  const int* src = (const int*)d_in[1];
  const int* dst = (const int*)d_in[2];
  const float* Ws = (const float*)d_in[3];
  const float* als = (const float*)d_in[4];
  const float* ars = (const float*)d_in[5];
  const float* bs = (const float*)d_in[6];
  const float* W_last = (const float*)d_in[7];
  const float* al_last = (const float*)d_in[8];
  const float* ar_last = (const float*)d_in[9];
  const float* b_last = (const float*)d_in[10];
  float* out = (float*)d_out;

  // ---- workspace layout ----
  float* h = (float*)d_ws;                        // 2,560,000 f
  float* el = h + 2560000;                        // 160,000
  float* er = el + 160000;                        // 160,000
  float* p = er + 160000;                         // 1,600,000
  float* wl = p + 1600000;                        // 1024
  float* wr = wl + 1024;                          // 1024
  float* mb = wr + 1024;                          // 128
  unsigned short* hb = (unsigned short*)(mb + 128);   // 2,560,000 us (16B-aligned)
  unsigned short* feat = hb + 2560000;                // 2,560,000 us
  unsigned short* g = feat + 2560000;                 // 20,480,000 us
  unsigned short* wsz = g + 20480000;                 // 32,768 us
  unsigned short* wpsz = wsz + 32768;                 // 131,072 us
  int* deg = (int*)(wpsz + 131072);
  int* off = deg + N_NODES;
  int* cursor = off + N_NODES + 1;
  int* csr_src = cursor + N_NODES;

  const int NHt = N_NODES * NH;  // 160000
  const int ND = N_NODES * DM;   // 2,560,000

  // CSR build
  hipMemsetAsync(deg, 0, sizeof(int) * N_NODES, stream);
  count_deg<<<(N_EDGES + 255) / 256, 256, 0, stream>>>(dst, deg);
  scan_deg<<<1, 1024, 0, stream>>>(deg, off, cursor);
  scatter_e<<<(N_EDGES + 255) / 256, 256, 0, stream>>>(src, dst, cursor, csr_src);

  // weight prep (independent of CSR)
  wswz_small<<<(2 * 16384 + 255) / 256, 256, 0, stream>>>(Ws, wsz);
  wswz_last<<<(131072 + 255) / 256, 256, 0, stream>>>(W_last, wpsz);
  wl_build<<<4, 256, 0, stream>>>(W_last, al_last, ar_last, b_last, wl, wr, mb);

  cast_x<<<(ND + 255) / 256, 256, 0, stream>>>(x, h, hb);

  const int GB = N_NODES / 32;  // 625
  for (int layer = 0; layer < 2; ++layer) {
    gemm_mfma<DM, false><<<GB, 256, 0, stream>>>(hb, wsz + layer * 16384, nullptr, nullptr,
                                                 feat, nullptr);
    attn_scores<<<(NHt + 255) / 256, 256, 0, stream>>>(feat, als + layer * NH * 16,
                                                       ars + layer * NH * 16, el, er);
    edge_softmax<<<(NHt + 255) / 256, 256, 0, stream>>>(off, csr_src, el, er, p);
    agg_small<<<N_NODES, 128, 0, stream>>>(off, csr_src, feat, p, bs + layer * DM, h, hb);
  }

  // last layer (aggregate-then-transform, mean folded into Wp)
  el_er_last<<<(NHt + 255) / 256, 256, 0, stream>>>(h, wl, wr, el, er);
  edge_softmax<<<(NHt + 255) / 256, 256, 0, stream>>>(off, csr_src, el, er, p);
  agg_last<<<N_NODES, 128, 0, stream>>>(off, csr_src, hb, p, g);
  gemm_mfma<NH * DM, true><<<GB, 256, 0, stream>>>(g, wpsz, h, mb, nullptr, out);
}

// Round 4
// 228.652 us; speedup vs baseline: 3.1686x; 1.3030x over previous
//
#include <hip/hip_runtime.h>
#include <math.h>

#define N_NODES 20000
#define N_EDGES 200000
#define DM 128
#define NH 8

typedef __attribute__((ext_vector_type(8))) short bf16x8;
typedef __attribute__((ext_vector_type(4))) float f32x4;

__device__ __forceinline__ unsigned short f2b(float f) {
  unsigned int u = __float_as_uint(f);
  unsigned int r = (u + 0x7FFFu + ((u >> 16) & 1u)) >> 16;  // RNE
  return (unsigned short)r;
}
__device__ __forceinline__ float b2f(unsigned short s) {
  return __uint_as_float(((unsigned int)s) << 16);
}

// ---------------- CSR build ----------------
__global__ void scan_deg(const int* __restrict__ deg, int* __restrict__ off,
                         int* __restrict__ cursor) {
  __shared__ int part[1024];
  const int tid = threadIdx.x;
  const int CHUNK = (N_NODES + 1023) / 1024;  // 20
  int base = tid * CHUNK;
  int s = 0;
  for (int i = 0; i < CHUNK; ++i) {
    int idx = base + i;
    if (idx < N_NODES) s += deg[idx];
  }
  part[tid] = s;
  __syncthreads();
  for (int ofs = 1; ofs < 1024; ofs <<= 1) {
    int v = (tid >= ofs) ? part[tid - ofs] : 0;
    __syncthreads();
    part[tid] += v;
    __syncthreads();
  }
  int run = (tid > 0) ? part[tid - 1] : 0;
  for (int i = 0; i < CHUNK; ++i) {
    int idx = base + i;
    if (idx < N_NODES) {
      off[idx] = run;
      cursor[idx] = run;
      run += deg[idx];
    }
  }
  if (tid == 0) off[N_NODES] = part[1023];
}

__global__ void scatter_e(const int* __restrict__ src, const int* __restrict__ dst,
                          int* __restrict__ cursor, int* __restrict__ csr_src) {
  int e = blockIdx.x * blockDim.x + threadIdx.x;
  if (e < N_EDGES) {
    int p = atomicAdd(&cursor[dst[e]], 1);
    csr_src[p] = src[e];
  }
}

// ---------------- fused prep: cast + deg count + weight swizzles ----------------
__global__ void prep_all(const float* __restrict__ x, float* __restrict__ h,
                         unsigned short* __restrict__ hb, const int* __restrict__ dst,
                         int* __restrict__ deg, const float* __restrict__ Ws,
                         unsigned short* __restrict__ wsz, const float* __restrict__ W_last,
                         unsigned short* __restrict__ wpsz, const float* __restrict__ al_last,
                         const float* __restrict__ ar_last, const float* __restrict__ b_last,
                         float* __restrict__ wl, float* __restrict__ wr,
                         float* __restrict__ mb) {
  int i = blockIdx.x * blockDim.x + threadIdx.x;
  if (i < N_NODES * DM) {
    float v = x[i];
    h[i] = v;
    hb[i] = f2b(v);
  }
  if (i < N_EDGES) atomicAdd(&deg[dst[i]], 1);
  if (i < 2 * 16384) {  // wswz_small
    int layer = i >> 14;
    int r = i & 16383;
    int j = r & 7, l = (r >> 3) & 63, f = (r >> 9) & 7, ks = r >> 12;
    int k = ks * 32 + ((l >> 4) << 3) + j;
    int n = f * 16 + (l & 15);
    wsz[i] = f2b(Ws[(size_t)layer * 16384 + k * 128 + n]);
  }
  if (i < 131072) {  // wswz_last (with 1/8 mean fold)
    int j = i & 7, l = (i >> 3) & 63, f = (i >> 9) & 7, ks = i >> 12;
    int k = ks * 32 + ((l >> 4) << 3) + j;
    int n = f * 16 + (l & 15);
    int h_ = k >> 7, ko = k & 127;
    wpsz[i] = f2b(W_last[(size_t)ko * 1024 + h_ * 128 + n] * 0.125f);
  }
  if (i < 1024) {  // wl_build
    int k = i >> 3, hh = i & 7;
    float sl = 0.f, sr = 0.f;
    for (int d = 0; d < 128; ++d) {
      float w = W_last[(size_t)k * 1024 + hh * 128 + d];
      sl += w * al_last[hh * 128 + d];
      sr += w * ar_last[hh * 128 + d];
    }
    wl[k * 8 + hh] = sl;
    wr[k * 8 + hh] = sr;
  }
  if (i < 128) {
    float s = 0.f;
#pragma unroll
    for (int hh = 0; hh < 8; ++hh) s += b_last[hh * 128 + i];
    mb[i] = s * 0.125f;
  }
}

// ---------------- MFMA GEMM ----------------
// block 256 = 4 waves; tile 32 rows x 128 cols; wave (wr,wc): rows wr*16.., cols wc*64..
// LAST=false: write feat bf16 + fused el/er epilogue. LAST=true: out = acc + hres + mb.
template <int K, bool LAST>
__global__ __launch_bounds__(256) void gemm_mfma(
    const unsigned short* __restrict__ A, const unsigned short* __restrict__ Bsz,
    const float* __restrict__ hres, const float* __restrict__ mb,
    unsigned short* __restrict__ Cb, float* __restrict__ Cf,
    const float* __restrict__ al, const float* __restrict__ ar,
    float* __restrict__ el, float* __restrict__ er) {
  const int tid = threadIdx.x;
  const int lane = tid & 63;
  const int wid = tid >> 6;
  const int wrow = wid & 1, wc = wid >> 1;
  const int r0 = blockIdx.x * 32;
  const int arow = r0 + wrow * 16 + (lane & 15);
  const int kg = lane >> 4;

  f32x4 acc[4];
#pragma unroll
  for (int fi = 0; fi < 4; ++fi) acc[fi] = {0.f, 0.f, 0.f, 0.f};

  const bf16x8* Ap = (const bf16x8*)(A + (size_t)arow * K + kg * 8);
  for (int ks = 0; ks < K / 32; ++ks) {
    bf16x8 a = Ap[ks * 4];
#pragma unroll
    for (int fi = 0; fi < 4; ++fi) {
      int f = wc * 4 + fi;
      bf16x8 b = *(const bf16x8*)(Bsz + (((size_t)(ks * 8 + f) * 64 + lane) << 3));
      acc[fi] = __builtin_amdgcn_mfma_f32_16x16x32_bf16(a, b, acc[fi], 0, 0, 0);
    }
  }

  const int rbase = r0 + wrow * 16 + (lane >> 4) * 4;
#pragma unroll
  for (int fi = 0; fi < 4; ++fi) {
    int col = wc * 64 + fi * 16 + (lane & 15);
#pragma unroll
    for (int r = 0; r < 4; ++r) {
      int row = rbase + r;
      float v = acc[fi][r];
      if (LAST)
        Cf[(size_t)row * DM + col] = v + hres[(size_t)row * DM + col] + mb[col];
      else
        Cb[(size_t)row * DM + col] = f2b(v);
    }
  }

  if (!LAST) {
    // fused attn scores: head hh = wc*4+fi owns cols hh*16..hh*16+15 = (lane&15)
#pragma unroll
    for (int fi = 0; fi < 4; ++fi) {
      int hh = wc * 4 + fi;
      float alv = al[hh * 16 + (lane & 15)];
      float arv = ar[hh * 16 + (lane & 15)];
#pragma unroll
      for (int r = 0; r < 4; ++r) {
        float pl = acc[fi][r] * alv;
        float pr = acc[fi][r] * arv;
#pragma unroll
        for (int msk = 1; msk < 16; msk <<= 1) {
          pl += __shfl_xor(pl, msk, 64);
          pr += __shfl_xor(pr, msk, 64);
        }
        if ((lane & 15) == 0) {
          int row = rbase + r;
          el[row * 8 + hh] = pl;
          er[row * 8 + hh] = pr;
        }
      }
    }
  }
}

// ---------------- last-layer attn scores: el/er = h @ wl/wr ----------------
__global__ void el_er_last(const float* __restrict__ hin, const float* __restrict__ wl,
                           const float* __restrict__ wr, float* __restrict__ el,
                           float* __restrict__ er) {
  int i = blockIdx.x * blockDim.x + threadIdx.x;
  if (i >= N_NODES * NH) return;
  int n = i >> 3, h = i & 7;
  const float* hr = hin + (size_t)n * 128;
  float sl = 0.f, sr = 0.f;
  for (int k = 0; k < 128; ++k) {
    float v = hr[k];
    sl += v * wl[k * 8 + h];
    sr += v * wr[k * 8 + h];
  }
  el[i] = sl;
  er[i] = sr;
}

// ---------------- fused edge-softmax + aggregation, wave per node ----------------
// lane = e_loc*8 + hh during softmax phases; lane = dim during aggregation.
__global__ __launch_bounds__(256) void fused_small(
    const int* __restrict__ off, const int* __restrict__ csr_src,
    const unsigned short* __restrict__ feat, const float* __restrict__ el,
    const float* __restrict__ er, const float* __restrict__ bias, float* __restrict__ h,
    unsigned short* __restrict__ hb) {
  const int t = blockIdx.x * 4 + (threadIdx.x >> 6);
  const int lane = threadIdx.x & 63;
  const int e_loc = lane >> 3, hh = lane & 7;
  const int beg = off[t], end = off[t + 1];
  const float ert = er[t * 8 + hh];

  // pass 1: online max + sum
  float m = -INFINITY, z = 0.f;
  for (int base = beg; base < end; base += 8) {
    int e = base + e_loc;
    int s = (e < end) ? csr_src[e] : 0;
    float v = -INFINITY;
    if (e < end) {
      float xv = el[s * 8 + hh] + ert;
      v = xv > 0.f ? xv : 0.2f * xv;
    }
    float cm = v;
    cm = fmaxf(cm, __shfl_xor(cm, 8, 64));
    cm = fmaxf(cm, __shfl_xor(cm, 16, 64));
    cm = fmaxf(cm, __shfl_xor(cm, 32, 64));
    float nm = fmaxf(m, cm);  // finite: chunk has >=1 real edge
    float ex = (e < end) ? __expf(v - nm) : 0.f;
    ex += __shfl_xor(ex, 8, 64);
    ex += __shfl_xor(ex, 16, 64);
    ex += __shfl_xor(ex, 32, 64);
    z = z * __expf(m - nm) + ex;
    m = nm;
  }
  float zi = (end > beg) ? 1.f / z : 0.f;

  // pass 2: alpha + gather-aggregate (dims d=lane, lane+64)
  float acc0 = 0.f, acc1 = 0.f;
  for (int base = beg; base < end; base += 8) {
    int e = base + e_loc;
    int s = (e < end) ? csr_src[e] : 0;
    float a = 0.f;
    if (e < end) {
      float xv = el[s * 8 + hh] + ert;
      xv = xv > 0.f ? xv : 0.2f * xv;
      a = __expf(xv - m) * zi;
    }
#pragma unroll
    for (int e2 = 0; e2 < 8; ++e2) {
      int s2 = __shfl(s, e2 * 8, 64);
      float a0 = __shfl(a, e2 * 8 + (lane >> 4), 64);
      float a1 = __shfl(a, e2 * 8 + 4 + (lane >> 4), 64);
      float f0 = b2f(feat[(size_t)s2 * 128 + lane]);
      float f1 = b2f(feat[(size_t)s2 * 128 + 64 + lane]);
      acc0 += a0 * f0;
      acc1 += a1 * f1;
    }
  }

  // epilogue: residual + ELU
  float v0 = acc0 + bias[lane];
  float v1 = acc1 + bias[lane + 64];
  v0 = v0 > 0.f ? v0 : expm1f(v0);
  v1 = v1 > 0.f ? v1 : expm1f(v1);
  size_t idx = (size_t)t * 128;
  float nh0 = h[idx + lane] + v0;
  float nh1 = h[idx + lane + 64] + v1;
  h[idx + lane] = nh0;
  h[idx + lane + 64] = nh1;
  hb[idx + lane] = f2b(nh0);
  hb[idx + lane + 64] = f2b(nh1);
}

// last layer: g[t, hh*128+k] = bf16( sum_e alpha[e,hh] * hb[src,k] )
__global__ __launch_bounds__(256) void fused_last(
    const int* __restrict__ off, const int* __restrict__ csr_src,
    const unsigned short* __restrict__ hb, const float* __restrict__ el,
    const float* __restrict__ er, unsigned short* __restrict__ g) {
  const int t = blockIdx.x * 4 + (threadIdx.x >> 6);
  const int lane = threadIdx.x & 63;
  const int e_loc = lane >> 3, hh = lane & 7;
  const int beg = off[t], end = off[t + 1];
  const float ert = er[t * 8 + hh];

  float m = -INFINITY, z = 0.f;
  for (int base = beg; base < end; base += 8) {
    int e = base + e_loc;
    int s = (e < end) ? csr_src[e] : 0;
    float v = -INFINITY;
    if (e < end) {
      float xv = el[s * 8 + hh] + ert;
      v = xv > 0.f ? xv : 0.2f * xv;
    }
    float cm = v;
    cm = fmaxf(cm, __shfl_xor(cm, 8, 64));
    cm = fmaxf(cm, __shfl_xor(cm, 16, 64));
    cm = fmaxf(cm, __shfl_xor(cm, 32, 64));
    float nm = fmaxf(m, cm);
    float ex = (e < end) ? __expf(v - nm) : 0.f;
    ex += __shfl_xor(ex, 8, 64);
    ex += __shfl_xor(ex, 16, 64);
    ex += __shfl_xor(ex, 32, 64);
    z = z * __expf(m - nm) + ex;
    m = nm;
  }
  float zi = (end > beg) ? 1.f / z : 0.f;

  float accA[8], accB[8];
#pragma unroll
  for (int k = 0; k < 8; ++k) accA[k] = accB[k] = 0.f;

  for (int base = beg; base < end; base += 8) {
    int e = base + e_loc;
    int s = (e < end) ? csr_src[e] : 0;
    float a = 0.f;
    if (e < end) {
      float xv = el[s * 8 + hh] + ert;
      xv = xv > 0.f ? xv : 0.2f * xv;
      a = __expf(xv - m) * zi;
    }
#pragma unroll
    for (int e2 = 0; e2 < 8; ++e2) {
      int s2 = __shfl(s, e2 * 8, 64);
      float hv0 = b2f(hb[(size_t)s2 * 128 + lane]);
      float hv1 = b2f(hb[(size_t)s2 * 128 + 64 + lane]);
#pragma unroll
      for (int h2 = 0; h2 < 8; ++h2) {
        float ah = __shfl(a, e2 * 8 + h2, 64);
        accA[h2] += ah * hv0;
        accB[h2] += ah * hv1;
      }
    }
  }
#pragma unroll
  for (int h2 = 0; h2 < 8; ++h2) {
    g[(size_t)t * 1024 + h2 * 128 + lane] = f2b(accA[h2]);
    g[(size_t)t * 1024 + h2 * 128 + 64 + lane] = f2b(accB[h2]);
  }
}

extern "C" void kernel_launch(void* const* d_in, const int* in_sizes, int n_in,
                              void* d_out, int out_size, void* d_ws, size_t ws_size,
                              hipStream_t stream) {
  const float* x = (const float*)d_in[0];
  const int* src = (const int*)d_in[1];
  const int* dst = (const int*)d_in[2];
  const float* Ws = (const float*)d_in[3];
  const float* als = (const float*)d_in[4];
  const float* ars = (const float*)d_in[5];
  const float* bs = (const float*)d_in[6];
  const float* W_last = (const float*)d_in[7];
  const float* al_last = (const float*)d_in[8];
  const float* ar_last = (const float*)d_in[9];
  const float* b_last = (const float*)d_in[10];
  float* out = (float*)d_out;

  // ---- workspace layout ----
  float* h = (float*)d_ws;                           // 2,560,000 f
  float* el = h + 2560000;                           // 160,000
  float* er = el + 160000;                           // 160,000
  float* wl = er + 160000;                           // 1024
  float* wr = wl + 1024;                             // 1024
  float* mb = wr + 1024;                             // 128
  unsigned short* hb = (unsigned short*)(mb + 128);  // 2,560,000 us
  unsigned short* feat = hb + 2560000;               // 2,560,000 us
  unsigned short* g = feat + 2560000;                // 20,480,000 us
  unsigned short* wsz = g + 20480000;                // 32,768 us
  unsigned short* wpsz = wsz + 32768;                // 131,072 us
  int* deg = (int*)(wpsz + 131072);
  int* off = deg + N_NODES;
  int* cursor = off + N_NODES + 1;
  int* csr_src = cursor + N_NODES;

  const int ND = N_NODES * DM;  // 2,560,000

  hipMemsetAsync(deg, 0, sizeof(int) * N_NODES, stream);
  prep_all<<<(ND + 255) / 256, 256, 0, stream>>>(x, h, hb, dst, deg, Ws, wsz, W_last, wpsz,
                                                 al_last, ar_last, b_last, wl, wr, mb);
  scan_deg<<<1, 1024, 0, stream>>>(deg, off, cursor);
  scatter_e<<<(N_EDGES + 255) / 256, 256, 0, stream>>>(src, dst, cursor, csr_src);

  const int GB = N_NODES / 32;   // 625
  const int FB = N_NODES / 4;    // 5000 (4 waves/block, 1 node/wave)
  for (int layer = 0; layer < 2; ++layer) {
    gemm_mfma<DM, false><<<GB, 256, 0, stream>>>(hb, wsz + layer * 16384, nullptr, nullptr,
                                                 feat, nullptr, als + layer * NH * 16,
                                                 ars + layer * NH * 16, el, er);
    fused_small<<<FB, 256, 0, stream>>>(off, csr_src, feat, el, er, bs + layer * DM, h, hb);
  }

  el_er_last<<<(N_NODES * NH + 255) / 256, 256, 0, stream>>>(h, wl, wr, el, er);
  fused_last<<<FB, 256, 0, stream>>>(off, csr_src, hb, el, er, g);
  gemm_mfma<NH * DM, true><<<GB, 256, 0, stream>>>(g, wpsz, h, mb, nullptr, out, nullptr,
                                                   nullptr, nullptr, nullptr);
}

// Round 5
// 216.374 us; speedup vs baseline: 3.3484x; 1.0567x over previous
//
#include <hip/hip_runtime.h>
#include <math.h>

#define N_NODES 20000
#define N_EDGES 200000
#define DM 128
#define NH 8

typedef __attribute__((ext_vector_type(8))) short bf16x8;
typedef __attribute__((ext_vector_type(4))) float f32x4;

__device__ __forceinline__ unsigned short f2b(float f) {
  unsigned int u = __float_as_uint(f);
  unsigned int r = (u + 0x7FFFu + ((u >> 16) & 1u)) >> 16;  // RNE
  return (unsigned short)r;
}
__device__ __forceinline__ float b2f(unsigned short s) {
  return __uint_as_float(((unsigned int)s) << 16);
}

// ---------------- CSR build ----------------
__global__ void scan_deg(const int* __restrict__ deg, int* __restrict__ off,
                         int* __restrict__ cursor) {
  __shared__ int part[1024];
  const int tid = threadIdx.x;
  const int CHUNK = (N_NODES + 1023) / 1024;  // 20
  int base = tid * CHUNK;
  int s = 0;
  for (int i = 0; i < CHUNK; ++i) {
    int idx = base + i;
    if (idx < N_NODES) s += deg[idx];
  }
  part[tid] = s;
  __syncthreads();
  for (int ofs = 1; ofs < 1024; ofs <<= 1) {
    int v = (tid >= ofs) ? part[tid - ofs] : 0;
    __syncthreads();
    part[tid] += v;
    __syncthreads();
  }
  int run = (tid > 0) ? part[tid - 1] : 0;
  for (int i = 0; i < CHUNK; ++i) {
    int idx = base + i;
    if (idx < N_NODES) {
      off[idx] = run;
      cursor[idx] = run;
      run += deg[idx];
    }
  }
  if (tid == 0) off[N_NODES] = part[1023];
}

__global__ void scatter_e(const int* __restrict__ src, const int* __restrict__ dst,
                          int* __restrict__ cursor, int* __restrict__ csr_src) {
  int e = blockIdx.x * blockDim.x + threadIdx.x;
  if (e < N_EDGES) {
    int p = atomicAdd(&cursor[dst[e]], 1);
    csr_src[p] = src[e];
  }
}

// ---------------- fused prep ----------------
__global__ void prep_all(const float* __restrict__ x, float* __restrict__ h,
                         unsigned short* __restrict__ hb, const int* __restrict__ dst,
                         int* __restrict__ deg, const float* __restrict__ Ws,
                         unsigned short* __restrict__ wsz, const float* __restrict__ W_last,
                         unsigned short* __restrict__ wpsz, const float* __restrict__ al_last,
                         const float* __restrict__ ar_last, const float* __restrict__ b_last,
                         unsigned short* __restrict__ wlrsz, float* __restrict__ mb) {
  int i = blockIdx.x * blockDim.x + threadIdx.x;
  if (i < N_NODES * DM) {
    float v = x[i];
    h[i] = v;
    hb[i] = f2b(v);
  }
  if (i < N_EDGES) atomicAdd(&deg[dst[i]], 1);
  if (i < 2 * 16384) {  // layers 0/1 B swizzle
    int layer = i >> 14;
    int r = i & 16383;
    int j = r & 7, l = (r >> 3) & 63, f = (r >> 9) & 7, ks = r >> 12;
    int k = ks * 32 + ((l >> 4) << 3) + j;
    int n = f * 16 + (l & 15);
    wsz[i] = f2b(Ws[(size_t)layer * 16384 + k * 128 + n]);
  }
  if (i < 131072) {  // last-layer B swizzle (1/8 mean folded)
    int j = i & 7, l = (i >> 3) & 63, f = (i >> 9) & 7, ks = i >> 12;
    int k = ks * 32 + ((l >> 4) << 3) + j;
    int n = f * 16 + (l & 15);
    int h_ = k >> 7, ko = k & 127;
    wpsz[i] = f2b(W_last[(size_t)ko * 1024 + h_ * 128 + n] * 0.125f);
  }
  if (i < 2048) {  // wlr fragment build: B[k][n] = dot(W_last[k, hh*128+:], al/ar[hh])
    int j = i & 7, l = (i >> 3) & 63, ks = i >> 9;  // ks 0..3
    int k = ks * 32 + ((l >> 4) << 3) + j;          // 0..127
    int n = l & 15;
    int hh = n & 7;
    const float* av = (n < 8) ? (al_last + hh * 128) : (ar_last + hh * 128);
    float s = 0.f;
    for (int d = 0; d < 128; ++d) s += W_last[(size_t)k * 1024 + hh * 128 + d] * av[d];
    wlrsz[i] = f2b(s);
  }
  if (i < 128) {
    float s = 0.f;
#pragma unroll
    for (int hh = 0; hh < 8; ++hh) s += b_last[hh * 128 + i];
    mb[i] = s * 0.125f;
  }
}

// ---------------- MFMA GEMM ----------------
// block 256 = 4 waves; tile 32 rows x 128 cols.
// LAST=false: feat bf16 + fused elr epilogue. LAST=true: out = acc + hres + mb.
template <int K, bool LAST>
__global__ __launch_bounds__(256) void gemm_mfma(
    const unsigned short* __restrict__ A, const unsigned short* __restrict__ Bsz,
    const float* __restrict__ hres, const float* __restrict__ mb,
    unsigned short* __restrict__ Cb, float* __restrict__ Cf,
    const float* __restrict__ al, const float* __restrict__ ar,
    float* __restrict__ elr) {
  const int tid = threadIdx.x;
  const int lane = tid & 63;
  const int wid = tid >> 6;
  const int wrow = wid & 1, wc = wid >> 1;
  const int r0 = blockIdx.x * 32;
  const int arow = r0 + wrow * 16 + (lane & 15);
  const int kg = lane >> 4;

  f32x4 acc[4];
#pragma unroll
  for (int fi = 0; fi < 4; ++fi) acc[fi] = {0.f, 0.f, 0.f, 0.f};

  const bf16x8* Ap = (const bf16x8*)(A + (size_t)arow * K + kg * 8);
  for (int ks = 0; ks < K / 32; ++ks) {
    bf16x8 a = Ap[ks * 4];
#pragma unroll
    for (int fi = 0; fi < 4; ++fi) {
      int f = wc * 4 + fi;
      bf16x8 b = *(const bf16x8*)(Bsz + (((size_t)(ks * 8 + f) * 64 + lane) << 3));
      acc[fi] = __builtin_amdgcn_mfma_f32_16x16x32_bf16(a, b, acc[fi], 0, 0, 0);
    }
  }

  const int rbase = r0 + wrow * 16 + (lane >> 4) * 4;
#pragma unroll
  for (int fi = 0; fi < 4; ++fi) {
    int col = wc * 64 + fi * 16 + (lane & 15);
#pragma unroll
    for (int r = 0; r < 4; ++r) {
      int row = rbase + r;
      float v = acc[fi][r];
      if (LAST)
        Cf[(size_t)row * DM + col] = v + hres[(size_t)row * DM + col] + mb[col];
      else
        Cb[(size_t)row * DM + col] = f2b(v);
    }
  }

  if (!LAST) {
    // fused attn scores: head hh = wc*4+fi owns cols hh*16+(lane&15)
#pragma unroll
    for (int fi = 0; fi < 4; ++fi) {
      int hh = wc * 4 + fi;
      float alv = al[hh * 16 + (lane & 15)];
      float arv = ar[hh * 16 + (lane & 15)];
#pragma unroll
      for (int r = 0; r < 4; ++r) {
        float pl = acc[fi][r] * alv;
        float pr = acc[fi][r] * arv;
#pragma unroll
        for (int msk = 1; msk < 16; msk <<= 1) {
          pl += __shfl_xor(pl, msk, 64);
          pr += __shfl_xor(pr, msk, 64);
        }
        if ((lane & 15) == 0) {
          int row = rbase + r;
          elr[row * 16 + hh] = pl;
          elr[row * 16 + 8 + hh] = pr;
        }
      }
    }
  }
}

// ---------------- last-layer elr = hb @ [wl|wr] via MFMA ----------------
__global__ __launch_bounds__(256) void elr_last(const unsigned short* __restrict__ hb,
                                                const unsigned short* __restrict__ wlrsz,
                                                float* __restrict__ elr) {
  const int lane = threadIdx.x & 63;
  const int wid = threadIdx.x >> 6;
  const int r0 = blockIdx.x * 64 + wid * 16;
  const int arow = r0 + (lane & 15);
  const int kg = lane >> 4;
  f32x4 acc = {0.f, 0.f, 0.f, 0.f};
  int arowc = arow < N_NODES ? arow : N_NODES - 1;
  const bf16x8* Ap = (const bf16x8*)(hb + (size_t)arowc * 128 + kg * 8);
#pragma unroll
  for (int ks = 0; ks < 4; ++ks) {
    bf16x8 a = Ap[ks * 4];
    bf16x8 b = *(const bf16x8*)(wlrsz + (((size_t)ks * 64 + lane) << 3));
    acc = __builtin_amdgcn_mfma_f32_16x16x32_bf16(a, b, acc, 0, 0, 0);
  }
  const int col = lane & 15;
  const int rbase = r0 + (lane >> 4) * 4;
#pragma unroll
  for (int r = 0; r < 4; ++r) {
    int row = rbase + r;
    if (row < N_NODES) elr[row * 16 + col] = acc[r];
  }
}

// ---------------- fused edge-softmax + aggregation, wave per node ----------------
// elr layout: [n][0..7]=el, [n][8..15]=er. No max-subtraction (logits bounded O(3)).
__global__ __launch_bounds__(256) void fused_small(
    const int* __restrict__ off, const int* __restrict__ csr_src,
    const unsigned short* __restrict__ feat, const float* __restrict__ elr,
    const float* __restrict__ bias, float* __restrict__ h, unsigned short* __restrict__ hb) {
  __shared__ float a_lds[4][64];
  const int wid = threadIdx.x >> 6;
  const int t = blockIdx.x * 4 + wid;
  const int lane = threadIdx.x & 63;
  const int e_loc = lane >> 3, hh = lane & 7;
  const int h0 = lane >> 4;  // head for dim=lane; dim=lane+64 -> h0+4
  const int beg = off[t], end = off[t + 1];
  const float ert = elr[t * 16 + 8 + hh];

  // pass 1: z
  float z = 0.f;
  for (int base = beg; base < end; base += 8) {
    int e = base + e_loc;
    float ex = 0.f;
    if (e < end) {
      int s = csr_src[e];
      float xv = elr[s * 16 + hh] + ert;
      xv = xv > 0.f ? xv : 0.2f * xv;
      ex = __expf(xv);
    }
    ex += __shfl_xor(ex, 8, 64);
    ex += __shfl_xor(ex, 16, 64);
    ex += __shfl_xor(ex, 32, 64);
    z += ex;
  }
  float zi = (end > beg) ? 1.f / z : 0.f;

  // pass 2: alpha -> LDS, aggregate
  float acc0 = 0.f, acc1 = 0.f;
  for (int base = beg; base < end; base += 8) {
    int e = base + e_loc;
    int s = 0;
    float a = 0.f;
    if (e < end) {
      s = csr_src[e];
      float xv = elr[s * 16 + hh] + ert;
      xv = xv > 0.f ? xv : 0.2f * xv;
      a = __expf(xv) * zi;
    }
    a_lds[wid][lane] = a;
    __builtin_amdgcn_wave_barrier();
    asm volatile("s_waitcnt lgkmcnt(0)" ::: "memory");
    int n = min(8, end - base);
    for (int e2 = 0; e2 < n; ++e2) {
      int s2 = __shfl(s, e2 * 8, 64);
      float a0 = a_lds[wid][e2 * 8 + h0];
      float a1 = a_lds[wid][e2 * 8 + 4 + h0];
      acc0 += a0 * b2f(feat[(size_t)s2 * 128 + lane]);
      acc1 += a1 * b2f(feat[(size_t)s2 * 128 + 64 + lane]);
    }
    __builtin_amdgcn_wave_barrier();
  }

  float v0 = acc0 + bias[lane];
  float v1 = acc1 + bias[lane + 64];
  v0 = v0 > 0.f ? v0 : expm1f(v0);
  v1 = v1 > 0.f ? v1 : expm1f(v1);
  size_t idx = (size_t)t * 128;
  float nh0 = h[idx + lane] + v0;
  float nh1 = h[idx + lane + 64] + v1;
  h[idx + lane] = nh0;
  h[idx + lane + 64] = nh1;
  hb[idx + lane] = f2b(nh0);
  hb[idx + lane + 64] = f2b(nh1);
}

// last layer: g[t, hh*128+k] = bf16( sum_e alpha[e,hh] * hb[src,k] )
__global__ __launch_bounds__(256) void fused_last(
    const int* __restrict__ off, const int* __restrict__ csr_src,
    const unsigned short* __restrict__ hb, const float* __restrict__ elr,
    unsigned short* __restrict__ g) {
  __shared__ float a_lds[4][64];
  const int wid = threadIdx.x >> 6;
  const int t = blockIdx.x * 4 + wid;
  const int lane = threadIdx.x & 63;
  const int e_loc = lane >> 3, hh = lane & 7;
  const int beg = off[t], end = off[t + 1];
  const float ert = elr[t * 16 + 8 + hh];

  float z = 0.f;
  for (int base = beg; base < end; base += 8) {
    int e = base + e_loc;
    float ex = 0.f;
    if (e < end) {
      int s = csr_src[e];
      float xv = elr[s * 16 + hh] + ert;
      xv = xv > 0.f ? xv : 0.2f * xv;
      ex = __expf(xv);
    }
    ex += __shfl_xor(ex, 8, 64);
    ex += __shfl_xor(ex, 16, 64);
    ex += __shfl_xor(ex, 32, 64);
    z += ex;
  }
  float zi = (end > beg) ? 1.f / z : 0.f;

  float accA[8], accB[8];
#pragma unroll
  for (int k = 0; k < 8; ++k) accA[k] = accB[k] = 0.f;

  for (int base = beg; base < end; base += 8) {
    int e = base + e_loc;
    int s = 0;
    float a = 0.f;
    if (e < end) {
      s = csr_src[e];
      float xv = elr[s * 16 + hh] + ert;
      xv = xv > 0.f ? xv : 0.2f * xv;
      a = __expf(xv) * zi;
    }
    a_lds[wid][lane] = a;
    __builtin_amdgcn_wave_barrier();
    asm volatile("s_waitcnt lgkmcnt(0)" ::: "memory");
    int n = min(8, end - base);
    for (int e2 = 0; e2 < n; ++e2) {
      int s2 = __shfl(s, e2 * 8, 64);
      float4 pa = *(const float4*)&a_lds[wid][e2 * 8];
      float4 pb = *(const float4*)&a_lds[wid][e2 * 8 + 4];
      float hv0 = b2f(hb[(size_t)s2 * 128 + lane]);
      float hv1 = b2f(hb[(size_t)s2 * 128 + 64 + lane]);
      accA[0] += pa.x * hv0; accB[0] += pa.x * hv1;
      accA[1] += pa.y * hv0; accB[1] += pa.y * hv1;
      accA[2] += pa.z * hv0; accB[2] += pa.z * hv1;
      accA[3] += pa.w * hv0; accB[3] += pa.w * hv1;
      accA[4] += pb.x * hv0; accB[4] += pb.x * hv1;
      accA[5] += pb.y * hv0; accB[5] += pb.y * hv1;
      accA[6] += pb.z * hv0; accB[6] += pb.z * hv1;
      accA[7] += pb.w * hv0; accB[7] += pb.w * hv1;
    }
    __builtin_amdgcn_wave_barrier();
  }
#pragma unroll
  for (int h2 = 0; h2 < 8; ++h2) {
    g[(size_t)t * 1024 + h2 * 128 + lane] = f2b(accA[h2]);
    g[(size_t)t * 1024 + h2 * 128 + 64 + lane] = f2b(accB[h2]);
  }
}

extern "C" void kernel_launch(void* const* d_in, const int* in_sizes, int n_in,
                              void* d_out, int out_size, void* d_ws, size_t ws_size,
                              hipStream_t stream) {
  const float* x = (const float*)d_in[0];
  const int* src = (const int*)d_in[1];
  const int* dst = (const int*)d_in[2];
  const float* Ws = (const float*)d_in[3];
  const float* als = (const float*)d_in[4];
  const float* ars = (const float*)d_in[5];
  const float* bs = (const float*)d_in[6];
  const float* W_last = (const float*)d_in[7];
  const float* al_last = (const float*)d_in[8];
  const float* ar_last = (const float*)d_in[9];
  const float* b_last = (const float*)d_in[10];
  float* out = (float*)d_out;

  // ---- workspace layout ----
  float* h = (float*)d_ws;                           // 2,560,000 f
  float* elr = h + 2560000;                          // 320,000 f
  float* mb = elr + 320000;                          // 128 f
  unsigned short* hb = (unsigned short*)(mb + 128);  // 2,560,000 us
  unsigned short* feat = hb + 2560000;               // 2,560,000 us
  unsigned short* g = feat + 2560000;                // 20,480,000 us
  unsigned short* wsz = g + 20480000;                // 32,768 us
  unsigned short* wpsz = wsz + 32768;                // 131,072 us
  unsigned short* wlrsz = wpsz + 131072;             // 2,048 us
  int* deg = (int*)(wlrsz + 2048);
  int* off = deg + N_NODES;
  int* cursor = off + N_NODES + 1;
  int* csr_src = cursor + N_NODES;

  const int ND = N_NODES * DM;  // 2,560,000

  hipMemsetAsync(deg, 0, sizeof(int) * N_NODES, stream);
  prep_all<<<(ND + 255) / 256, 256, 0, stream>>>(x, h, hb, dst, deg, Ws, wsz, W_last, wpsz,
                                                 al_last, ar_last, b_last, wlrsz, mb);
  scan_deg<<<1, 1024, 0, stream>>>(deg, off, cursor);
  scatter_e<<<(N_EDGES + 255) / 256, 256, 0, stream>>>(src, dst, cursor, csr_src);

  const int GB = N_NODES / 32;  // 625
  const int FB = N_NODES / 4;   // 5000
  for (int layer = 0; layer < 2; ++layer) {
    gemm_mfma<DM, false><<<GB, 256, 0, stream>>>(hb, wsz + layer * 16384, nullptr, nullptr,
                                                 feat, nullptr, als + layer * NH * 16,
                                                 ars + layer * NH * 16, elr);
    fused_small<<<FB, 256, 0, stream>>>(off, csr_src, feat, elr, bs + layer * DM, h, hb);
  }

  elr_last<<<(N_NODES + 63) / 64, 256, 0, stream>>>(hb, wlrsz, elr);
  fused_last<<<FB, 256, 0, stream>>>(off, csr_src, hb, elr, g);
  gemm_mfma<NH * DM, true><<<GB, 256, 0, stream>>>(g, wpsz, h, mb, nullptr, out, nullptr,
                                                   nullptr, nullptr);
}

// Round 6
// 201.825 us; speedup vs baseline: 3.5898x; 1.0721x over previous
//
#include <hip/hip_runtime.h>
#include <math.h>

#define N_NODES 20000
#define N_EDGES 200000
#define DM 128
#define NH 8

typedef __attribute__((ext_vector_type(8))) short bf16x8;
typedef __attribute__((ext_vector_type(4))) float f32x4;

__device__ __forceinline__ unsigned short f2b(float f) {
  unsigned int u = __float_as_uint(f);
  unsigned int r = (u + 0x7FFFu + ((u >> 16) & 1u)) >> 16;  // RNE
  return (unsigned short)r;
}
__device__ __forceinline__ float b2f(unsigned short s) {
  return __uint_as_float(((unsigned int)s) << 16);
}

// ---------------- CSR build ----------------
__global__ void scan_deg(const int* __restrict__ deg, int* __restrict__ off,
                         int* __restrict__ cursor) {
  __shared__ int part[1024];
  const int tid = threadIdx.x;
  const int CHUNK = (N_NODES + 1023) / 1024;  // 20
  int base = tid * CHUNK;
  int s = 0;
  for (int i = 0; i < CHUNK; ++i) {
    int idx = base + i;
    if (idx < N_NODES) s += deg[idx];
  }
  part[tid] = s;
  __syncthreads();
  for (int ofs = 1; ofs < 1024; ofs <<= 1) {
    int v = (tid >= ofs) ? part[tid - ofs] : 0;
    __syncthreads();
    part[tid] += v;
    __syncthreads();
  }
  int run = (tid > 0) ? part[tid - 1] : 0;
  for (int i = 0; i < CHUNK; ++i) {
    int idx = base + i;
    if (idx < N_NODES) {
      off[idx] = run;
      cursor[idx] = run;
      run += deg[idx];
    }
  }
  if (tid == 0) off[N_NODES] = part[1023];
}

__global__ void scatter_e(const int* __restrict__ src, const int* __restrict__ dst,
                          int* __restrict__ cursor, int* __restrict__ csr_src) {
  int e = blockIdx.x * blockDim.x + threadIdx.x;
  if (e < N_EDGES) {
    int p = atomicAdd(&cursor[dst[e]], 1);
    csr_src[p] = src[e];
  }
}

// ---------------- fused prep ----------------
__global__ void prep_all(const float* __restrict__ x, float* __restrict__ h,
                         unsigned short* __restrict__ hb, const int* __restrict__ dst,
                         int* __restrict__ deg, const float* __restrict__ Ws,
                         unsigned short* __restrict__ wsz, const float* __restrict__ W_last,
                         unsigned short* __restrict__ wpsz, const float* __restrict__ al_last,
                         const float* __restrict__ ar_last, const float* __restrict__ b_last,
                         unsigned short* __restrict__ wlrsz, float* __restrict__ mb) {
  int i = blockIdx.x * blockDim.x + threadIdx.x;
  if (i < N_NODES * DM) {
    float v = x[i];
    h[i] = v;
    hb[i] = f2b(v);
  }
  if (i < N_EDGES) atomicAdd(&deg[dst[i]], 1);
  if (i < 2 * 16384) {  // layers 0/1 B swizzle
    int layer = i >> 14;
    int r = i & 16383;
    int j = r & 7, l = (r >> 3) & 63, f = (r >> 9) & 7, ks = r >> 12;
    int k = ks * 32 + ((l >> 4) << 3) + j;
    int n = f * 16 + (l & 15);
    wsz[i] = f2b(Ws[(size_t)layer * 16384 + k * 128 + n]);
  }
  if (i < 131072) {  // last-layer B swizzle (1/8 mean folded)
    int j = i & 7, l = (i >> 3) & 63, f = (i >> 9) & 7, ks = i >> 12;
    int k = ks * 32 + ((l >> 4) << 3) + j;
    int n = f * 16 + (l & 15);
    int h_ = k >> 7, ko = k & 127;
    wpsz[i] = f2b(W_last[(size_t)ko * 1024 + h_ * 128 + n] * 0.125f);
  }
  if (i < 2048) {  // wlr fragment build
    int j = i & 7, l = (i >> 3) & 63, ks = i >> 9;
    int k = ks * 32 + ((l >> 4) << 3) + j;
    int n = l & 15;
    int hh = n & 7;
    const float* av = (n < 8) ? (al_last + hh * 128) : (ar_last + hh * 128);
    float s = 0.f;
    for (int d = 0; d < 128; ++d) s += W_last[(size_t)k * 1024 + hh * 128 + d] * av[d];
    wlrsz[i] = f2b(s);
  }
  if (i < 128) {
    float s = 0.f;
#pragma unroll
    for (int hh = 0; hh < 8; ++hh) s += b_last[hh * 128 + i];
    mb[i] = s * 0.125f;
  }
}

// ---------------- MFMA GEMM ----------------
template <int K, bool LAST>
__global__ __launch_bounds__(256) void gemm_mfma(
    const unsigned short* __restrict__ A, const unsigned short* __restrict__ Bsz,
    const float* __restrict__ hres, const float* __restrict__ mb,
    unsigned short* __restrict__ Cb, float* __restrict__ Cf,
    const float* __restrict__ al, const float* __restrict__ ar,
    float* __restrict__ elr) {
  const int tid = threadIdx.x;
  const int lane = tid & 63;
  const int wid = tid >> 6;
  const int wrow = wid & 1, wc = wid >> 1;
  const int r0 = blockIdx.x * 32;
  const int arow = r0 + wrow * 16 + (lane & 15);
  const int kg = lane >> 4;

  f32x4 acc[4];
#pragma unroll
  for (int fi = 0; fi < 4; ++fi) acc[fi] = {0.f, 0.f, 0.f, 0.f};

  const bf16x8* Ap = (const bf16x8*)(A + (size_t)arow * K + kg * 8);
  for (int ks = 0; ks < K / 32; ++ks) {
    bf16x8 a = Ap[ks * 4];
#pragma unroll
    for (int fi = 0; fi < 4; ++fi) {
      int f = wc * 4 + fi;
      bf16x8 b = *(const bf16x8*)(Bsz + (((size_t)(ks * 8 + f) * 64 + lane) << 3));
      acc[fi] = __builtin_amdgcn_mfma_f32_16x16x32_bf16(a, b, acc[fi], 0, 0, 0);
    }
  }

  const int rbase = r0 + wrow * 16 + (lane >> 4) * 4;
#pragma unroll
  for (int fi = 0; fi < 4; ++fi) {
    int col = wc * 64 + fi * 16 + (lane & 15);
#pragma unroll
    for (int r = 0; r < 4; ++r) {
      int row = rbase + r;
      float v = acc[fi][r];
      if (LAST)
        Cf[(size_t)row * DM + col] = v + hres[(size_t)row * DM + col] + mb[col];
      else
        Cb[(size_t)row * DM + col] = f2b(v);
    }
  }

  if (!LAST) {
#pragma unroll
    for (int fi = 0; fi < 4; ++fi) {
      int hh = wc * 4 + fi;
      float alv = al[hh * 16 + (lane & 15)];
      float arv = ar[hh * 16 + (lane & 15)];
#pragma unroll
      for (int r = 0; r < 4; ++r) {
        float pl = acc[fi][r] * alv;
        float pr = acc[fi][r] * arv;
#pragma unroll
        for (int msk = 1; msk < 16; msk <<= 1) {
          pl += __shfl_xor(pl, msk, 64);
          pr += __shfl_xor(pr, msk, 64);
        }
        if ((lane & 15) == 0) {
          int row = rbase + r;
          elr[row * 16 + hh] = pl;
          elr[row * 16 + 8 + hh] = pr;
        }
      }
    }
  }
}

// ---------------- last-layer elr = hb @ [wl|wr] via MFMA ----------------
__global__ __launch_bounds__(256) void elr_last(const unsigned short* __restrict__ hb,
                                                const unsigned short* __restrict__ wlrsz,
                                                float* __restrict__ elr) {
  const int lane = threadIdx.x & 63;
  const int wid = threadIdx.x >> 6;
  const int r0 = blockIdx.x * 64 + wid * 16;
  const int arow = r0 + (lane & 15);
  const int kg = lane >> 4;
  f32x4 acc = {0.f, 0.f, 0.f, 0.f};
  int arowc = arow < N_NODES ? arow : N_NODES - 1;
  const bf16x8* Ap = (const bf16x8*)(hb + (size_t)arowc * 128 + kg * 8);
#pragma unroll
  for (int ks = 0; ks < 4; ++ks) {
    bf16x8 a = Ap[ks * 4];
    bf16x8 b = *(const bf16x8*)(wlrsz + (((size_t)ks * 64 + lane) << 3));
    acc = __builtin_amdgcn_mfma_f32_16x16x32_bf16(a, b, acc, 0, 0, 0);
  }
  const int col = lane & 15;
  const int rbase = r0 + (lane >> 4) * 4;
#pragma unroll
  for (int r = 0; r < 4; ++r) {
    int row = rbase + r;
    if (row < N_NODES) elr[row * 16 + col] = acc[r];
  }
}

// ---------------- fused edge-softmax + aggregation, SINGLE PASS ----------------
// No max-subtraction -> numerators fixed -> aggregate unnormalized, scale by 1/z at end.
__global__ __launch_bounds__(256) void fused_small(
    const int* __restrict__ off, const int* __restrict__ csr_src,
    const unsigned short* __restrict__ feat, const float* __restrict__ elr,
    const float* __restrict__ bias, float* __restrict__ h, unsigned short* __restrict__ hb) {
  __shared__ float a_lds[4][64];
  __shared__ int s_lds[4][8];
  __shared__ float zi_lds[4][8];
  const int wid = threadIdx.x >> 6;
  const int t = blockIdx.x * 4 + wid;
  const int lane = threadIdx.x & 63;
  const int e_loc = lane >> 3, hh = lane & 7;
  const int h0 = lane >> 4;  // head for dim=lane; dim=lane+64 -> h0+4
  const int beg = off[t], end = off[t + 1];
  const float ert = elr[t * 16 + 8 + hh];

  float z = 0.f, acc0 = 0.f, acc1 = 0.f;
  for (int base = beg; base < end; base += 8) {
    int e = base + e_loc;
    int s = 0;
    float ex = 0.f;
    if (e < end) {
      s = csr_src[e];
      float xv = elr[s * 16 + hh] + ert;
      xv = xv > 0.f ? xv : 0.2f * xv;
      ex = __expf(xv);
    }
    a_lds[wid][lane] = ex;
    if (hh == 0) s_lds[wid][e_loc] = s;
    __builtin_amdgcn_wave_barrier();
    asm volatile("s_waitcnt lgkmcnt(0)" ::: "memory");
    z += ex;
    int n = min(8, end - base);
    for (int e2 = 0; e2 < n; ++e2) {
      int s2 = s_lds[wid][e2];
      float a0 = a_lds[wid][e2 * 8 + h0];
      float a1 = a_lds[wid][e2 * 8 + 4 + h0];
      acc0 += a0 * b2f(feat[(size_t)s2 * 128 + lane]);
      acc1 += a1 * b2f(feat[(size_t)s2 * 128 + 64 + lane]);
    }
    __builtin_amdgcn_wave_barrier();
  }
  z += __shfl_xor(z, 8, 64);
  z += __shfl_xor(z, 16, 64);
  z += __shfl_xor(z, 32, 64);
  if (e_loc == 0) zi_lds[wid][hh] = (z > 0.f) ? 1.f / z : 0.f;
  __builtin_amdgcn_wave_barrier();
  asm volatile("s_waitcnt lgkmcnt(0)" ::: "memory");
  acc0 *= zi_lds[wid][h0];
  acc1 *= zi_lds[wid][h0 + 4];

  float v0 = acc0 + bias[lane];
  float v1 = acc1 + bias[lane + 64];
  v0 = v0 > 0.f ? v0 : expm1f(v0);
  v1 = v1 > 0.f ? v1 : expm1f(v1);
  size_t idx = (size_t)t * 128;
  float nh0 = h[idx + lane] + v0;
  float nh1 = h[idx + lane + 64] + v1;
  h[idx + lane] = nh0;
  h[idx + lane + 64] = nh1;
  hb[idx + lane] = f2b(nh0);
  hb[idx + lane + 64] = f2b(nh1);
}

// last layer: g[t, hh*128+k] = bf16( (sum_e ex[e,hh] * hb[src,k]) / z[hh] )
__global__ __launch_bounds__(256) void fused_last(
    const int* __restrict__ off, const int* __restrict__ csr_src,
    const unsigned short* __restrict__ hb, const float* __restrict__ elr,
    unsigned short* __restrict__ g) {
  __shared__ float a_lds[4][64];
  __shared__ int s_lds[4][8];
  __shared__ float zi_lds[4][8];
  const int wid = threadIdx.x >> 6;
  const int t = blockIdx.x * 4 + wid;
  const int lane = threadIdx.x & 63;
  const int e_loc = lane >> 3, hh = lane & 7;
  const int beg = off[t], end = off[t + 1];
  const float ert = elr[t * 16 + 8 + hh];

  float z = 0.f;
  float accA[8], accB[8];
#pragma unroll
  for (int k = 0; k < 8; ++k) accA[k] = accB[k] = 0.f;

  for (int base = beg; base < end; base += 8) {
    int e = base + e_loc;
    int s = 0;
    float ex = 0.f;
    if (e < end) {
      s = csr_src[e];
      float xv = elr[s * 16 + hh] + ert;
      xv = xv > 0.f ? xv : 0.2f * xv;
      ex = __expf(xv);
    }
    a_lds[wid][lane] = ex;
    if (hh == 0) s_lds[wid][e_loc] = s;
    __builtin_amdgcn_wave_barrier();
    asm volatile("s_waitcnt lgkmcnt(0)" ::: "memory");
    z += ex;
    int n = min(8, end - base);
    for (int e2 = 0; e2 < n; ++e2) {
      int s2 = s_lds[wid][e2];
      float4 pa = *(const float4*)&a_lds[wid][e2 * 8];
      float4 pb = *(const float4*)&a_lds[wid][e2 * 8 + 4];
      float hv0 = b2f(hb[(size_t)s2 * 128 + lane]);
      float hv1 = b2f(hb[(size_t)s2 * 128 + 64 + lane]);
      accA[0] += pa.x * hv0; accB[0] += pa.x * hv1;
      accA[1] += pa.y * hv0; accB[1] += pa.y * hv1;
      accA[2] += pa.z * hv0; accB[2] += pa.z * hv1;
      accA[3] += pa.w * hv0; accB[3] += pa.w * hv1;
      accA[4] += pb.x * hv0; accB[4] += pb.x * hv1;
      accA[5] += pb.y * hv0; accB[5] += pb.y * hv1;
      accA[6] += pb.z * hv0; accB[6] += pb.z * hv1;
      accA[7] += pb.w * hv0; accB[7] += pb.w * hv1;
    }
    __builtin_amdgcn_wave_barrier();
  }
  z += __shfl_xor(z, 8, 64);
  z += __shfl_xor(z, 16, 64);
  z += __shfl_xor(z, 32, 64);
  if (e_loc == 0) zi_lds[wid][hh] = (z > 0.f) ? 1.f / z : 0.f;
  __builtin_amdgcn_wave_barrier();
  asm volatile("s_waitcnt lgkmcnt(0)" ::: "memory");
  float4 zia = *(const float4*)&zi_lds[wid][0];
  float4 zib = *(const float4*)&zi_lds[wid][4];
  float ziv[8] = {zia.x, zia.y, zia.z, zia.w, zib.x, zib.y, zib.z, zib.w};
#pragma unroll
  for (int h2 = 0; h2 < 8; ++h2) {
    g[(size_t)t * 1024 + h2 * 128 + lane] = f2b(accA[h2] * ziv[h2]);
    g[(size_t)t * 1024 + h2 * 128 + 64 + lane] = f2b(accB[h2] * ziv[h2]);
  }
}

extern "C" void kernel_launch(void* const* d_in, const int* in_sizes, int n_in,
                              void* d_out, int out_size, void* d_ws, size_t ws_size,
                              hipStream_t stream) {
  const float* x = (const float*)d_in[0];
  const int* src = (const int*)d_in[1];
  const int* dst = (const int*)d_in[2];
  const float* Ws = (const float*)d_in[3];
  const float* als = (const float*)d_in[4];
  const float* ars = (const float*)d_in[5];
  const float* bs = (const float*)d_in[6];
  const float* W_last = (const float*)d_in[7];
  const float* al_last = (const float*)d_in[8];
  const float* ar_last = (const float*)d_in[9];
  const float* b_last = (const float*)d_in[10];
  float* out = (float*)d_out;

  // ---- workspace layout ----
  float* h = (float*)d_ws;                           // 2,560,000 f
  float* elr = h + 2560000;                          // 320,000 f
  float* mb = elr + 320000;                          // 128 f
  unsigned short* hb = (unsigned short*)(mb + 128);  // 2,560,000 us
  unsigned short* feat = hb + 2560000;               // 2,560,000 us
  unsigned short* g = feat + 2560000;                // 20,480,000 us
  unsigned short* wsz = g + 20480000;                // 32,768 us
  unsigned short* wpsz = wsz + 32768;                // 131,072 us
  unsigned short* wlrsz = wpsz + 131072;             // 2,048 us
  int* deg = (int*)(wlrsz + 2048);
  int* off = deg + N_NODES;
  int* cursor = off + N_NODES + 1;
  int* csr_src = cursor + N_NODES;

  const int ND = N_NODES * DM;  // 2,560,000

  hipMemsetAsync(deg, 0, sizeof(int) * N_NODES, stream);
  prep_all<<<(ND + 255) / 256, 256, 0, stream>>>(x, h, hb, dst, deg, Ws, wsz, W_last, wpsz,
                                                 al_last, ar_last, b_last, wlrsz, mb);
  scan_deg<<<1, 1024, 0, stream>>>(deg, off, cursor);
  scatter_e<<<(N_EDGES + 255) / 256, 256, 0, stream>>>(src, dst, cursor, csr_src);

  const int GB = N_NODES / 32;  // 625
  const int FB = N_NODES / 4;   // 5000
  for (int layer = 0; layer < 2; ++layer) {
    gemm_mfma<DM, false><<<GB, 256, 0, stream>>>(hb, wsz + layer * 16384, nullptr, nullptr,
                                                 feat, nullptr, als + layer * NH * 16,
                                                 ars + layer * NH * 16, elr);
    fused_small<<<FB, 256, 0, stream>>>(off, csr_src, feat, elr, bs + layer * DM, h, hb);
  }

  elr_last<<<(N_NODES + 63) / 64, 256, 0, stream>>>(hb, wlrsz, elr);
  fused_last<<<FB, 256, 0, stream>>>(off, csr_src, hb, elr, g);
  gemm_mfma<NH * DM, true><<<GB, 256, 0, stream>>>(g, wpsz, h, mb, nullptr, out, nullptr,
                                                   nullptr, nullptr);
}